// Round 13
// baseline (686.804 us; speedup 1.0000x reference)
//
#include <hip/hip_runtime.h>
#include <hip/hip_cooperative_groups.h>
#include <math.h>

namespace cg = cooperative_groups;

#define N 4096
#define D 512
#define L 128

// ---------------- fast path ----------------
// dist via v_sad_u8 on 8-bit fixed-point (scale 16, bias 128), packed
// 4 dims per u32, transposed layouts [pd][N]. v_sad family ~4cyc/wave64 on
// gfx950 (R3/R4). dist pinned ~144us across 5 schedules (R4-R10) -> ceiling.
// u16 dist interface (R7); fused prep (R9); topk+loss fused (R11).
// R13: ONE cooperative kernel. R12's occupancy guard silently failed (split
// ran); __launch_bounds__(256,4) now statically guarantees 4 blocks/CU so
// the cooperative launch is unconditional.
#define NP8 (D / 4)      // 128 packed dims (4 bytes each)
#define BI 64            // rows per dist tile (16 per wave)
#define BJ 256           // cols per dist tile (4 per lane)
#define MGRID 1024       // cooperative grid (4 blocks/CU on 256 CUs)

// ---------------- fallback path (exact f32, ~25 MB ws) ----------------
#define PARTS 16
#define PARTJ (N / PARTS)
#define TI 128
#define TJ 64
#define KD 32
#define AS_STRIDE (TI + 4)
#define BS_STRIDE (TJ + 4)
#define DS_STRIDE (TJ + 4)
#define SMEM_FLOATS (TI * DS_STRIDE)

__device__ __forceinline__ unsigned sad8(unsigned a, unsigned b, unsigned c) {
#if __has_builtin(__builtin_amdgcn_sad_u8)
  return __builtin_amdgcn_sad_u8(a, b, c);
#else
  unsigned d;
  asm("v_sad_u8 %0, %1, %2, %3" : "=v"(d) : "v"(a), "v"(b), "v"(c));
  return d;
#endif
}

// quantize one float to u8 code (scale 16, bias 128) — must match everywhere
__device__ __forceinline__ unsigned q8(float x) {
  int q = __float2int_rn(x * 16.0f);
  q = min(max(q, -128), 127) + 128;
  return (unsigned)q;
}

// Insert v into ascending sorted tk[0..15], dropping the old max (f32).
__device__ __forceinline__ void topk_insert(float (&tk)[16], float v) {
  float x = v;
#pragma unroll
  for (int k = 0; k < 16; ++k) {
    float lo = fminf(x, tk[k]);
    float hi = fmaxf(x, tk[k]);
    tk[k] = lo;
    x = hi;
  }
}

// u32 variant.
__device__ __forceinline__ void topk_insert_u32(unsigned (&tk)[16], unsigned v) {
  unsigned x = v;
#pragma unroll
  for (int k = 0; k < 16; ++k) {
    unsigned lo = tk[k] < x ? tk[k] : x;
    unsigned hi = tk[k] < x ? x : tk[k];
    tk[k] = lo;
    x = hi;
  }
}

// Wave-level top-16 of one u16 dist row -> score (all lanes return same).
__device__ __forceinline__ float row_score(const unsigned* __restrict__ p,
                                           int lane) {
  unsigned tk[16];
#pragma unroll
  for (int k = 0; k < 16; ++k) tk[k] = 0xFFFFFFFFu;

#pragma unroll 1
  for (int q = 0; q < 8; ++q) {  // each q: wave reads 1 KB contiguous
    uint4 v = *(const uint4*)(p + q * 256 + lane * 4);
    unsigned v0 = v.x & 0xFFFFu, v1 = v.x >> 16;
    unsigned v2 = v.y & 0xFFFFu, v3 = v.y >> 16;
    unsigned v4 = v.z & 0xFFFFu, v5 = v.z >> 16;
    unsigned v6 = v.w & 0xFFFFu, v7 = v.w >> 16;
    if (v0 < tk[15]) topk_insert_u32(tk, v0);
    if (v1 < tk[15]) topk_insert_u32(tk, v1);
    if (v2 < tk[15]) topk_insert_u32(tk, v2);
    if (v3 < tk[15]) topk_insert_u32(tk, v3);
    if (v4 < tk[15]) topk_insert_u32(tk, v4);
    if (v5 < tk[15]) topk_insert_u32(tk, v5);
    if (v6 < tk[15]) topk_insert_u32(tk, v6);
    if (v7 < tk[15]) topk_insert_u32(tk, v7);
  }

  // recursive-doubling merge: after all levels, all 64 lanes identical
#pragma unroll
  for (int m = 1; m < 64; m <<= 1) {
    unsigned oth[16];
#pragma unroll
    for (int k = 0; k < 16; ++k)
      oth[k] = (unsigned)__shfl_xor((int)tk[k], m, 64);
    unsigned lo[16];
#pragma unroll
    for (int k = 0; k < 16; ++k)
      lo[k] = tk[k] < oth[15 - k] ? tk[k] : oth[15 - k];
#pragma unroll
    for (int dlt = 8; dlt >= 1; dlt >>= 1) {
#pragma unroll
      for (int i = 0; i < 16; ++i) {
        if ((i & dlt) == 0 && (i + dlt) < 16) {
          unsigned a = lo[i], b = lo[i + dlt];
          lo[i] = a < b ? a : b;
          lo[i + dlt] = a < b ? b : a;
        }
      }
    }
#pragma unroll
    for (int k = 0; k < 16; ++k) tk[k] = lo[k];
  }

  // dist = acc/16 ; 1/dist = 16/acc (exact: acc < 2^24)
  float s = 0.f;
#pragma unroll
  for (int k = 0; k < 16; ++k) s += 16.0f / (float)tk[k];
  return s * (1.0f / 16.0f);
}

// prep one 8-row unit of one source into dst[pd][N] (R9's proven body).
template <bool IS_GT>
__device__ __forceinline__ void prep_unit(
    const float* __restrict__ src_gt, const float* __restrict__ lat,
    const float* __restrict__ W, const float* __restrict__ bias,
    unsigned* __restrict__ dst, int r0, int t, float* ls) {
  const int lane = t & 63;
  float vals[8][2];

  if (IS_GT) {
#pragma unroll
    for (int r = 0; r < 8; ++r) {
      vals[r][0] = src_gt[(size_t)(r0 + r) * D + t];
      vals[r][1] = src_gt[(size_t)(r0 + r) * D + t + 256];
    }
  } else {
    __syncthreads();  // ls reuse guard
    {
      float4 v = *(const float4*)(lat + (size_t)r0 * L + t * 4);
      *(float4*)&ls[t * 4] = v;
    }
    __syncthreads();

    float acc[8][2];
#pragma unroll
    for (int r = 0; r < 8; ++r) { acc[r][0] = 0.f; acc[r][1] = 0.f; }

#pragma unroll 4
    for (int l = 0; l < L; ++l) {
      float w0 = W[l * D + t];
      float w1 = W[l * D + t + 256];
#pragma unroll
      for (int r = 0; r < 8; ++r) {
        float x = ls[r * L + l];
        acc[r][0] = fmaf(x, w0, acc[r][0]);
        acc[r][1] = fmaf(x, w1, acc[r][1]);
      }
    }
    float b0 = bias[t], b1 = bias[t + 256];
#pragma unroll
    for (int r = 0; r < 8; ++r) {
      vals[r][0] = acc[r][0] + b0;
      vals[r][1] = acc[r][1] + b1;
    }
  }

  // quantize + shfl-pack + transposed store
#pragma unroll
  for (int h = 0; h < 2; ++h) {
    const int pd = (t >> 2) + h * 64;
#pragma unroll
    for (int r = 0; r < 8; ++r) {
      unsigned u = q8(vals[r][h]);
      unsigned p2 = u | (((unsigned)__shfl_down((int)u, 1, 64)) << 8);
      unsigned w4 = p2 | (((unsigned)__shfl_down((int)p2, 2, 64)) << 16);
      if ((lane & 3) == 0) dst[(size_t)pd * N + r0 + r] = w4;
    }
  }
}

// One dist tile (R9's proven 144us body — at ceiling).
__device__ __forceinline__ void dist_tile(
    const unsigned* __restrict__ Aq, const unsigned* __restrict__ Bq,
    unsigned short* __restrict__ out, int i0, int j0, int tid) {
  const int wave = tid >> 6;
  const int lane = tid & 63;
  const int iw = __builtin_amdgcn_readfirstlane(i0 + wave * 16);

  const unsigned* __restrict__ ap = Aq + iw;            // uniform per wave
  const unsigned* __restrict__ bp = Bq + j0 + 4 * lane; // coalesced per wave

  unsigned acc[16][4];
#pragma unroll
  for (int r = 0; r < 16; ++r)
#pragma unroll
    for (int c = 0; c < 4; ++c) acc[r][c] = 0u;

  uint4 a0c = *(const uint4*)(ap);
  uint4 a1c = *(const uint4*)(ap + 4);
  uint4 a2c = *(const uint4*)(ap + 8);
  uint4 a3c = *(const uint4*)(ap + 12);
  ap += N;
  uint4 bcur = *(const uint4*)(bp);
  bp += N;

#pragma unroll 2
  for (int pd = 0; pd < NP8; ++pd) {
    uint4 a0n, a1n, a2n, a3n, bnext;
    if (pd + 1 < NP8) {
      a0n = *(const uint4*)(ap);
      a1n = *(const uint4*)(ap + 4);
      a2n = *(const uint4*)(ap + 8);
      a3n = *(const uint4*)(ap + 12);
      ap += N;
      bnext = *(const uint4*)(bp);
      bp += N;
    }
#define SADQ(q, base)                                       \
    acc[base + 0][0] = sad8(q.x, bcur.x, acc[base + 0][0]); \
    acc[base + 0][1] = sad8(q.x, bcur.y, acc[base + 0][1]); \
    acc[base + 0][2] = sad8(q.x, bcur.z, acc[base + 0][2]); \
    acc[base + 0][3] = sad8(q.x, bcur.w, acc[base + 0][3]); \
    acc[base + 1][0] = sad8(q.y, bcur.x, acc[base + 1][0]); \
    acc[base + 1][1] = sad8(q.y, bcur.y, acc[base + 1][1]); \
    acc[base + 1][2] = sad8(q.y, bcur.z, acc[base + 1][2]); \
    acc[base + 1][3] = sad8(q.y, bcur.w, acc[base + 1][3]); \
    acc[base + 2][0] = sad8(q.z, bcur.x, acc[base + 2][0]); \
    acc[base + 2][1] = sad8(q.z, bcur.y, acc[base + 2][1]); \
    acc[base + 2][2] = sad8(q.z, bcur.z, acc[base + 2][2]); \
    acc[base + 2][3] = sad8(q.z, bcur.w, acc[base + 2][3]); \
    acc[base + 3][0] = sad8(q.w, bcur.x, acc[base + 3][0]); \
    acc[base + 3][1] = sad8(q.w, bcur.y, acc[base + 3][1]); \
    acc[base + 3][2] = sad8(q.w, bcur.z, acc[base + 3][2]); \
    acc[base + 3][3] = sad8(q.w, bcur.w, acc[base + 3][3]);
    SADQ(a0c, 0) SADQ(a1c, 4) SADQ(a2c, 8) SADQ(a3c, 12)
#undef SADQ
    a0c = a0n; a1c = a1n; a2c = a2n; a3c = a3n;
    bcur = bnext;
  }

#pragma unroll
  for (int r = 0; r < 16; ++r) {
    unsigned p0 = (acc[r][0] > 65535u ? 65535u : acc[r][0]) |
                  ((acc[r][1] > 65535u ? 65535u : acc[r][1]) << 16);
    unsigned p1 = (acc[r][2] > 65535u ? 65535u : acc[r][2]) |
                  ((acc[r][3] > 65535u ? 65535u : acc[r][3]) << 16);
    *(uint2*)(out + (size_t)(iw + r) * N + j0 + 4 * lane) = make_uint2(p0, p1);
  }
}

// ============ ONE COOPERATIVE KERNEL: prep -> dist -> scores -> loss ======
// __launch_bounds__(256, 4): 4 waves/EU min => 4 blocks/CU statically
// guaranteed => 1024-block cooperative grid always fits (256 CUs).
__global__ __launch_bounds__(256, 4) void mega_kernel(
    const float* __restrict__ gt, const float* __restrict__ lat_test,
    const float* __restrict__ lat_train, const float* __restrict__ W,
    const float* __restrict__ bias, unsigned* __restrict__ Gq,
    unsigned* __restrict__ Aq, unsigned* __restrict__ Tq,
    unsigned short* __restrict__ dist, float* __restrict__ partials,
    float* __restrict__ out) {
  cg::grid_group grid = cg::this_grid();
  const int b = blockIdx.x;
  const int t = threadIdx.x;
  const int wave = t >> 6;
  const int lane = t & 63;

  __shared__ float ls[8 * L];  // phase A staging / phase C+D partials

  // ---- phase A: prep 1536 units (512 per source) over MGRID blocks ----
  for (int u = b; u < 1536; u += MGRID) {
    const int which = u >> 9;
    const int r0 = (u & 511) * 8;
    if (which == 0)
      prep_unit<true>(gt, nullptr, W, bias, Gq, r0, t, ls);
    else if (which == 1)
      prep_unit<false>(nullptr, lat_test, W, bias, Aq, r0, t, ls);
    else
      prep_unit<false>(nullptr, lat_train, W, bias, Tq, r0, t, ls);
  }
  grid.sync();

  // ---- phase B: dist 2048 tiles over MGRID blocks (exactly 2 each) ----
  for (int tt = b; tt < 2048; tt += MGRID) {
    const int mat = tt >> 10;
    const int rem = tt & 1023;
    const int i0 = (rem & 63) * BI;
    const int j0 = (rem >> 6) * BJ;
    dist_tile(Aq, mat ? Tq : Gq, dist + (size_t)mat * N * N, i0, j0, t);
  }
  grid.sync();

  // ---- phase C: 4096 waves -> row scores -> per-block partial ----
  {
    const int row = b * 4 + wave;
    const unsigned* p_pos = (const unsigned*)(dist + (size_t)row * N);
    const unsigned* p_neg = (const unsigned*)(dist + ((size_t)N + row) * N);
    float pos = row_score(p_pos, lane);
    float neg = row_score(p_neg, lane);
    float l = fmaxf(neg - pos, 0.f);
    float h = (l <= 1.f) ? 0.5f * l * l : (l - 0.5f);
    __syncthreads();  // ls free (phase A long done for this block)
    if (lane == 0) ls[wave] = h;
    __syncthreads();
    if (t == 0) partials[b] = ls[0] + ls[1] + ls[2] + ls[3];
  }
  grid.sync();

  // ---- phase D: block 0 reduces partials -> out (single writer) ----
  if (b == 0) {
    float s = 0.f;
    for (int i = t; i < MGRID; i += 256) s += partials[i];
#pragma unroll
    for (int off = 32; off > 0; off >>= 1) s += __shfl_down(s, off, 64);
    __syncthreads();
    if (lane == 0) ls[wave] = s;
    __syncthreads();
    if (t == 0) out[0] = (ls[0] + ls[1] + ls[2] + ls[3]) * (1.0f / (float)N);
  }
}

// ============ SPLIT-KERNEL fast path (R11, proven 274us) ============
__global__ __launch_bounds__(256) void prep_kernel(
    const float* __restrict__ gt, const float* __restrict__ lat_test,
    const float* __restrict__ lat_train, const float* __restrict__ W,
    const float* __restrict__ bias, unsigned* __restrict__ Gq,
    unsigned* __restrict__ Aq, unsigned* __restrict__ Tq) {
  const int which = blockIdx.y;
  unsigned* __restrict__ dst = which == 0 ? Gq : (which == 1 ? Aq : Tq);
  const int r0 = blockIdx.x * 8;
  const int t = threadIdx.x;
  __shared__ float ls[8 * L];
  if (which == 0)
    prep_unit<true>(gt, nullptr, W, bias, dst, r0, t, ls);
  else
    prep_unit<false>(nullptr, which == 1 ? lat_test : lat_train, W, bias, dst,
                     r0, t, ls);
}

__global__ __launch_bounds__(256) void dist_sad_kernel(
    const unsigned* __restrict__ Aq, const unsigned* __restrict__ Gq,
    const unsigned* __restrict__ Tq, unsigned short* __restrict__ dist) {
  const int mat = blockIdx.z;
  dist_tile(Aq, mat ? Tq : Gq, dist + (size_t)mat * N * N, blockIdx.x * BI,
            blockIdx.y * BJ, (int)threadIdx.x);
}

__global__ __launch_bounds__(256) void topk_loss_kernel(
    const unsigned short* __restrict__ dist, float* __restrict__ out) {
  const int wave = threadIdx.x >> 6;
  const int lane = threadIdx.x & 63;
  const int row = blockIdx.x * 4 + wave;

  const unsigned* p_pos = (const unsigned*)(dist + (size_t)row * N);
  const unsigned* p_neg = (const unsigned*)(dist + ((size_t)N + row) * N);

  float pos = row_score(p_pos, lane);
  float neg = row_score(p_neg, lane);

  float l = fmaxf(neg - pos, 0.f);
  float h = (l <= 1.f) ? 0.5f * l * l : (l - 0.5f);

  __shared__ float ws[4];
  if (lane == 0) ws[wave] = h;
  __syncthreads();
  if (threadIdx.x == 0) {
    float t = (ws[0] + ws[1] + ws[2] + ws[3]) * (1.0f / (float)N);
    atomicAdd(out, t);
  }
}

// ============ FALLBACK PATH (exact f32, proven) ============
__global__ __launch_bounds__(256) void linear_kernel(
    const float* __restrict__ lat_test, const float* __restrict__ lat_train,
    const float* __restrict__ W, const float* __restrict__ bias,
    float* __restrict__ rec_test, float* __restrict__ rec_train) {
  const float* __restrict__ lat = blockIdx.y ? lat_train : lat_test;
  float* __restrict__ out = blockIdx.y ? rec_train : rec_test;
  const int r0 = blockIdx.x * 8;
  const int t = threadIdx.x;

  __shared__ float ls[8 * L];
  {
    float4 v = *(const float4*)(lat + (size_t)r0 * L + t * 4);
    *(float4*)&ls[t * 4] = v;
  }
  __syncthreads();

  float acc[8][2];
#pragma unroll
  for (int r = 0; r < 8; ++r) { acc[r][0] = 0.f; acc[r][1] = 0.f; }

#pragma unroll 4
  for (int l = 0; l < L; ++l) {
    float w0 = W[l * D + t];
    float w1 = W[l * D + t + 256];
#pragma unroll
    for (int r = 0; r < 8; ++r) {
      float x = ls[r * L + l];
      acc[r][0] = fmaf(x, w0, acc[r][0]);
      acc[r][1] = fmaf(x, w1, acc[r][1]);
    }
  }
  float b0 = bias[t], b1 = bias[t + 256];
#pragma unroll
  for (int r = 0; r < 8; ++r) {
    out[(size_t)(r0 + r) * D + t] = acc[r][0] + b0;
    out[(size_t)(r0 + r) * D + t + 256] = acc[r][1] + b1;
  }
}

__global__ __launch_bounds__(256) void dist_topk_kernel(
    const float* __restrict__ Arec, const float* __restrict__ Bgt,
    const float* __restrict__ Btr, float* __restrict__ cand) {
  const int itile = blockIdx.x;
  const int part = blockIdx.y;
  const int mat = blockIdx.z;
  const float* __restrict__ B = mat ? Btr : Bgt;
  const int i0 = itile * TI;
  const int jbase = part * PARTJ;

  __shared__ float smem[SMEM_FLOATS];
  float* As = smem;
  float* Bs = smem + KD * AS_STRIDE;
  float* distS = smem;

  const int tid = threadIdx.x;
  const int tx = tid & 15;
  const int ty = tid >> 4;
  const int srow = tid >> 1;
  const int shalf = tid & 1;
  const int scol = shalf * 32;

  float tk[16];
#pragma unroll
  for (int k = 0; k < 16; ++k) tk[k] = 3.0e38f;

  for (int jc = 0; jc < PARTJ; jc += TJ) {
    float acc[8][4];
#pragma unroll
    for (int r = 0; r < 8; ++r)
#pragma unroll
      for (int c = 0; c < 4; ++c) acc[r][c] = 0.f;

    for (int d0 = 0; d0 < D; d0 += KD) {
      __syncthreads();
#pragma unroll
      for (int s = 0; s < 4; ++s) {
        int f4 = tid + s * 256;
        int r = f4 >> 3;
        int c4 = f4 & 7;
        float4 v = *(const float4*)(Arec + (size_t)(i0 + r) * D + d0 + c4 * 4);
        As[(4 * c4 + 0) * AS_STRIDE + r] = v.x;
        As[(4 * c4 + 1) * AS_STRIDE + r] = v.y;
        As[(4 * c4 + 2) * AS_STRIDE + r] = v.z;
        As[(4 * c4 + 3) * AS_STRIDE + r] = v.w;
      }
#pragma unroll
      for (int s = 0; s < 2; ++s) {
        int f4 = tid + s * 256;
        int r = f4 >> 3;
        int c4 = f4 & 7;
        float4 v = *(const float4*)(B + (size_t)(jbase + jc + r) * D + d0 + c4 * 4);
        Bs[(4 * c4 + 0) * BS_STRIDE + r] = v.x;
        Bs[(4 * c4 + 1) * BS_STRIDE + r] = v.y;
        Bs[(4 * c4 + 2) * BS_STRIDE + r] = v.z;
        Bs[(4 * c4 + 3) * BS_STRIDE + r] = v.w;
      }
      __syncthreads();

#pragma unroll
      for (int d = 0; d < KD; ++d) {
        float4 a0 = *(const float4*)&As[d * AS_STRIDE + 8 * ty];
        float4 a1 = *(const float4*)&As[d * AS_STRIDE + 8 * ty + 4];
        float4 bv4 = *(const float4*)&Bs[d * BS_STRIDE + 4 * tx];
        float av[8] = {a0.x, a0.y, a0.z, a0.w, a1.x, a1.y, a1.z, a1.w};
        float bv[4] = {bv4.x, bv4.y, bv4.z, bv4.w};
#pragma unroll
        for (int r = 0; r < 8; ++r)
#pragma unroll
          for (int c = 0; c < 4; ++c) acc[r][c] += __builtin_fabsf(av[r] - bv[c]);
      }
    }

    __syncthreads();
#pragma unroll
    for (int r = 0; r < 8; ++r)
      *(float4*)&distS[(8 * ty + r) * DS_STRIDE + 4 * tx] =
          make_float4(acc[r][0], acc[r][1], acc[r][2], acc[r][3]);
    __syncthreads();

#pragma unroll 1
    for (int j4 = 0; j4 < 8; ++j4) {
      float4 v = *(const float4*)&distS[srow * DS_STRIDE + scol + j4 * 4];
      if (v.x < tk[15]) topk_insert(tk, v.x);
      if (v.y < tk[15]) topk_insert(tk, v.y);
      if (v.z < tk[15]) topk_insert(tk, v.z);
      if (v.w < tk[15]) topk_insert(tk, v.w);
    }
  }

  __syncthreads();
  float* mergeS = smem;
#pragma unroll
  for (int k4 = 0; k4 < 4; ++k4)
    *(float4*)&mergeS[srow * 32 + shalf * 16 + k4 * 4] =
        make_float4(tk[k4 * 4], tk[k4 * 4 + 1], tk[k4 * 4 + 2], tk[k4 * 4 + 3]);
  __syncthreads();

  if (tid < TI) {
    const float* LA = &mergeS[tid * 32];
    const float* LB = LA + 16;
    const int row = i0 + tid;
    float* dst = cand + ((size_t)((mat * PARTS + part) * N) + row) * 16;
    int ia = 0, ib = 0;
#pragma unroll 1
    for (int k = 0; k < 16; ++k) {
      float a = LA[ia < 16 ? ia : 15];
      float b = LB[ib < 16 ? ib : 15];
      bool takeA = (ib >= 16) || (ia < 16 && a <= b);
      dst[k] = takeA ? a : b;
      ia += takeA ? 1 : 0;
      ib += takeA ? 0 : 1;
    }
  }
}

__global__ __launch_bounds__(256) void merge_kernel(
    const float* __restrict__ cand, float* __restrict__ scores) {
  const int gid = blockIdx.x * 256 + threadIdx.x;
  if (gid >= 2 * N) return;
  const int m = gid >> 12;
  const int row = gid & (N - 1);

  float tk[16];
#pragma unroll
  for (int k = 0; k < 16; ++k) tk[k] = 3.0e38f;

  for (int p = 0; p < PARTS; ++p) {
    const float* lp = cand + ((size_t)((m * PARTS + p) * N) + row) * 16;
#pragma unroll 1
    for (int k = 0; k < 16; ++k) {
      float v = lp[k];
      if (v >= tk[15]) break;
      topk_insert(tk, v);
    }
  }
  float s = 0.f;
#pragma unroll
  for (int k = 0; k < 16; ++k) s += 1.0f / tk[k];
  scores[(size_t)m * N + row] = s * (1.0f / 16.0f);
}

__global__ __launch_bounds__(256) void loss_kernel(
    const float* __restrict__ scores, float* __restrict__ out) {
  const int tid = threadIdx.x;
  float s = 0.f;
  for (int i = tid; i < N; i += 256) {
    float l = scores[N + i] - scores[i];
    l = fmaxf(l, 0.f);
    s += (l <= 1.f) ? 0.5f * l * l : (l - 0.5f);
  }
#pragma unroll
  for (int off = 32; off > 0; off >>= 1) s += __shfl_down(s, off, 64);
  __shared__ float ws[4];
  if ((tid & 63) == 0) ws[tid >> 6] = s;
  __syncthreads();
  if (tid == 0) {
    float t = ws[0] + ws[1] + ws[2] + ws[3];
    out[0] = t * (1.0f / (float)N);
  }
}

extern "C" void kernel_launch(void* const* d_in, const int* in_sizes, int n_in,
                              void* d_out, int out_size, void* d_ws, size_t ws_size,
                              hipStream_t stream) {
  const float* gt_vals = (const float*)d_in[0];
  const float* train_latent = (const float*)d_in[1];
  const float* test_latent = (const float*)d_in[2];
  const float* W = (const float*)d_in[3];
  const float* b = (const float*)d_in[4];
  float* out = (float*)d_out;

  char* ws = (char*)d_ws;
  const size_t MB = 1048576;
  const size_t REC = 8 * MB;
  const size_t NEED_FAST = 80 * MB;

  if (ws_size >= NEED_FAST) {
    // layout: [0,2M) Aq(test), [2,4M) Tq(train), [4,6M) Gq(gt),
    // [6M,+4K) partials, [8M,72M) dist u16 (2 * 4096^2 * 2B = 64 MiB).
    unsigned* Aq = (unsigned*)(ws);
    unsigned* Tq = (unsigned*)(ws + 2 * MB);
    unsigned* Gq = (unsigned*)(ws + 4 * MB);
    float* partials = (float*)(ws + 6 * MB);
    unsigned short* dist16 = (unsigned short*)(ws + 8 * MB);

    void* args[] = {(void*)&gt_vals, (void*)&test_latent,
                    (void*)&train_latent, (void*)&W, (void*)&b,
                    (void*)&Gq, (void*)&Aq, (void*)&Tq, (void*)&dist16,
                    (void*)&partials, (void*)&out};
    hipError_t err = hipLaunchCooperativeKernel(
        (void*)mega_kernel, dim3(MGRID), dim3(256), args, 0, stream);
    if (err != hipSuccess) {
      // proven R11 split path
      hipMemsetAsync(out, 0, sizeof(float), stream);
      prep_kernel<<<dim3(N / 8, 3), 256, 0, stream>>>(
          gt_vals, test_latent, train_latent, W, b, Gq, Aq, Tq);
      dist_sad_kernel<<<dim3(N / BI, N / BJ, 2), 256, 0, stream>>>(
          Aq, Gq, Tq, dist16);
      topk_loss_kernel<<<N / 4, 256, 0, stream>>>(dist16, out);
    }
  } else {
    float* rec_test = (float*)(ws);
    float* rec_train = (float*)(ws + REC);
    float* cand = (float*)(ws + 2 * REC);                 // 8 MB
    float* scores = (float*)(ws + 2 * REC + 8388608);     // 32 KB
    linear_kernel<<<dim3(N / 8, 2), 256, 0, stream>>>(
        test_latent, train_latent, W, b, rec_test, rec_train);
    dist_topk_kernel<<<dim3(N / TI, PARTS, 2), 256, 0, stream>>>(
        rec_test, gt_vals, rec_train, cand);
    merge_kernel<<<(2 * N) / 256, 256, 0, stream>>>(cand, scores);
    loss_kernel<<<1, 256, 0, stream>>>(scores, out);
  }
}

// Round 14
// 273.783 us; speedup vs baseline: 2.5086x; 2.5086x over previous
//
#include <hip/hip_runtime.h>
#include <math.h>

#define N 4096
#define D 512
#define L 128

// ---------------- fast path ----------------
// dist via v_sad_u8 on 8-bit fixed-point (scale 16, bias 128), packed
// 4 dims per u32, transposed layouts [pd][N]. v_sad family ~4cyc/wave64 on
// gfx950 (R3/R4). dist pinned ~144us across 5 schedules (R4-R10) -> ceiling.
// u16 dist interface (R7); fused prep (R9); topk+loss fused (R11).
// R13: cooperative mega-kernel REFUTED (636us; grid.sync forces cross-XCD
// L2 drain, FETCH 19.7->62MB, VALUBusy 28%). R14: split path, memset
// dispatch removed (prep zeroes out[0]) -> 3 dispatches.
#define NP8 (D / 4)      // 128 packed dims (4 bytes each)
#define BI 64            // rows per dist tile (16 per wave)
#define BJ 256           // cols per dist tile (4 per lane)

// ---------------- fallback path (exact f32, ~25 MB ws) ----------------
#define PARTS 16
#define PARTJ (N / PARTS)
#define TI 128
#define TJ 64
#define KD 32
#define AS_STRIDE (TI + 4)
#define BS_STRIDE (TJ + 4)
#define DS_STRIDE (TJ + 4)
#define SMEM_FLOATS (TI * DS_STRIDE)

__device__ __forceinline__ unsigned sad8(unsigned a, unsigned b, unsigned c) {
#if __has_builtin(__builtin_amdgcn_sad_u8)
  return __builtin_amdgcn_sad_u8(a, b, c);
#else
  unsigned d;
  asm("v_sad_u8 %0, %1, %2, %3" : "=v"(d) : "v"(a), "v"(b), "v"(c));
  return d;
#endif
}

// quantize one float to u8 code (scale 16, bias 128) — must match everywhere
__device__ __forceinline__ unsigned q8(float x) {
  int q = __float2int_rn(x * 16.0f);
  q = min(max(q, -128), 127) + 128;
  return (unsigned)q;
}

// Insert v into ascending sorted tk[0..15], dropping the old max (f32).
__device__ __forceinline__ void topk_insert(float (&tk)[16], float v) {
  float x = v;
#pragma unroll
  for (int k = 0; k < 16; ++k) {
    float lo = fminf(x, tk[k]);
    float hi = fmaxf(x, tk[k]);
    tk[k] = lo;
    x = hi;
  }
}

// u32 variant.
__device__ __forceinline__ void topk_insert_u32(unsigned (&tk)[16], unsigned v) {
  unsigned x = v;
#pragma unroll
  for (int k = 0; k < 16; ++k) {
    unsigned lo = tk[k] < x ? tk[k] : x;
    unsigned hi = tk[k] < x ? x : tk[k];
    tk[k] = lo;
    x = hi;
  }
}

// Wave-level top-16 of one u16 dist row -> score (all lanes return same).
__device__ __forceinline__ float row_score(const unsigned* __restrict__ p,
                                           int lane) {
  unsigned tk[16];
#pragma unroll
  for (int k = 0; k < 16; ++k) tk[k] = 0xFFFFFFFFu;

#pragma unroll 1
  for (int q = 0; q < 8; ++q) {  // each q: wave reads 1 KB contiguous
    uint4 v = *(const uint4*)(p + q * 256 + lane * 4);
    unsigned v0 = v.x & 0xFFFFu, v1 = v.x >> 16;
    unsigned v2 = v.y & 0xFFFFu, v3 = v.y >> 16;
    unsigned v4 = v.z & 0xFFFFu, v5 = v.z >> 16;
    unsigned v6 = v.w & 0xFFFFu, v7 = v.w >> 16;
    if (v0 < tk[15]) topk_insert_u32(tk, v0);
    if (v1 < tk[15]) topk_insert_u32(tk, v1);
    if (v2 < tk[15]) topk_insert_u32(tk, v2);
    if (v3 < tk[15]) topk_insert_u32(tk, v3);
    if (v4 < tk[15]) topk_insert_u32(tk, v4);
    if (v5 < tk[15]) topk_insert_u32(tk, v5);
    if (v6 < tk[15]) topk_insert_u32(tk, v6);
    if (v7 < tk[15]) topk_insert_u32(tk, v7);
  }

  // recursive-doubling merge: after all levels, all 64 lanes identical
#pragma unroll
  for (int m = 1; m < 64; m <<= 1) {
    unsigned oth[16];
#pragma unroll
    for (int k = 0; k < 16; ++k)
      oth[k] = (unsigned)__shfl_xor((int)tk[k], m, 64);
    unsigned lo[16];
#pragma unroll
    for (int k = 0; k < 16; ++k)
      lo[k] = tk[k] < oth[15 - k] ? tk[k] : oth[15 - k];
#pragma unroll
    for (int dlt = 8; dlt >= 1; dlt >>= 1) {
#pragma unroll
      for (int i = 0; i < 16; ++i) {
        if ((i & dlt) == 0 && (i + dlt) < 16) {
          unsigned a = lo[i], b = lo[i + dlt];
          lo[i] = a < b ? a : b;
          lo[i + dlt] = a < b ? b : a;
        }
      }
    }
#pragma unroll
    for (int k = 0; k < 16; ++k) tk[k] = lo[k];
  }

  // dist = acc/16 ; 1/dist = 16/acc (exact: acc < 2^24)
  float s = 0.f;
#pragma unroll
  for (int k = 0; k < 16; ++k) s += 16.0f / (float)tk[k];
  return s * (1.0f / 16.0f);
}

// prep one 8-row unit of one source into dst[pd][N] (R9's proven body).
template <bool IS_GT>
__device__ __forceinline__ void prep_unit(
    const float* __restrict__ src_gt, const float* __restrict__ lat,
    const float* __restrict__ W, const float* __restrict__ bias,
    unsigned* __restrict__ dst, int r0, int t, float* ls) {
  const int lane = t & 63;
  float vals[8][2];

  if (IS_GT) {
#pragma unroll
    for (int r = 0; r < 8; ++r) {
      vals[r][0] = src_gt[(size_t)(r0 + r) * D + t];
      vals[r][1] = src_gt[(size_t)(r0 + r) * D + t + 256];
    }
  } else {
    {
      float4 v = *(const float4*)(lat + (size_t)r0 * L + t * 4);
      *(float4*)&ls[t * 4] = v;
    }
    __syncthreads();

    float acc[8][2];
#pragma unroll
    for (int r = 0; r < 8; ++r) { acc[r][0] = 0.f; acc[r][1] = 0.f; }

#pragma unroll 4
    for (int l = 0; l < L; ++l) {
      float w0 = W[l * D + t];
      float w1 = W[l * D + t + 256];
#pragma unroll
      for (int r = 0; r < 8; ++r) {
        float x = ls[r * L + l];
        acc[r][0] = fmaf(x, w0, acc[r][0]);
        acc[r][1] = fmaf(x, w1, acc[r][1]);
      }
    }
    float b0 = bias[t], b1 = bias[t + 256];
#pragma unroll
    for (int r = 0; r < 8; ++r) {
      vals[r][0] = acc[r][0] + b0;
      vals[r][1] = acc[r][1] + b1;
    }
  }

  // quantize + shfl-pack + transposed store
#pragma unroll
  for (int h = 0; h < 2; ++h) {
    const int pd = (t >> 2) + h * 64;
#pragma unroll
    for (int r = 0; r < 8; ++r) {
      unsigned u = q8(vals[r][h]);
      unsigned p2 = u | (((unsigned)__shfl_down((int)u, 1, 64)) << 8);
      unsigned w4 = p2 | (((unsigned)__shfl_down((int)p2, 2, 64)) << 16);
      if ((lane & 3) == 0) dst[(size_t)pd * N + r0 + r] = w4;
    }
  }
}

// One dist tile (R9's proven 144us body — at ceiling).
__device__ __forceinline__ void dist_tile(
    const unsigned* __restrict__ Aq, const unsigned* __restrict__ Bq,
    unsigned short* __restrict__ out, int i0, int j0, int tid) {
  const int wave = tid >> 6;
  const int lane = tid & 63;
  const int iw = __builtin_amdgcn_readfirstlane(i0 + wave * 16);

  const unsigned* __restrict__ ap = Aq + iw;            // uniform per wave
  const unsigned* __restrict__ bp = Bq + j0 + 4 * lane; // coalesced per wave

  unsigned acc[16][4];
#pragma unroll
  for (int r = 0; r < 16; ++r)
#pragma unroll
    for (int c = 0; c < 4; ++c) acc[r][c] = 0u;

  uint4 a0c = *(const uint4*)(ap);
  uint4 a1c = *(const uint4*)(ap + 4);
  uint4 a2c = *(const uint4*)(ap + 8);
  uint4 a3c = *(const uint4*)(ap + 12);
  ap += N;
  uint4 bcur = *(const uint4*)(bp);
  bp += N;

#pragma unroll 2
  for (int pd = 0; pd < NP8; ++pd) {
    uint4 a0n, a1n, a2n, a3n, bnext;
    if (pd + 1 < NP8) {
      a0n = *(const uint4*)(ap);
      a1n = *(const uint4*)(ap + 4);
      a2n = *(const uint4*)(ap + 8);
      a3n = *(const uint4*)(ap + 12);
      ap += N;
      bnext = *(const uint4*)(bp);
      bp += N;
    }
#define SADQ(q, base)                                       \
    acc[base + 0][0] = sad8(q.x, bcur.x, acc[base + 0][0]); \
    acc[base + 0][1] = sad8(q.x, bcur.y, acc[base + 0][1]); \
    acc[base + 0][2] = sad8(q.x, bcur.z, acc[base + 0][2]); \
    acc[base + 0][3] = sad8(q.x, bcur.w, acc[base + 0][3]); \
    acc[base + 1][0] = sad8(q.y, bcur.x, acc[base + 1][0]); \
    acc[base + 1][1] = sad8(q.y, bcur.y, acc[base + 1][1]); \
    acc[base + 1][2] = sad8(q.y, bcur.z, acc[base + 1][2]); \
    acc[base + 1][3] = sad8(q.y, bcur.w, acc[base + 1][3]); \
    acc[base + 2][0] = sad8(q.z, bcur.x, acc[base + 2][0]); \
    acc[base + 2][1] = sad8(q.z, bcur.y, acc[base + 2][1]); \
    acc[base + 2][2] = sad8(q.z, bcur.z, acc[base + 2][2]); \
    acc[base + 2][3] = sad8(q.z, bcur.w, acc[base + 2][3]); \
    acc[base + 3][0] = sad8(q.w, bcur.x, acc[base + 3][0]); \
    acc[base + 3][1] = sad8(q.w, bcur.y, acc[base + 3][1]); \
    acc[base + 3][2] = sad8(q.w, bcur.z, acc[base + 3][2]); \
    acc[base + 3][3] = sad8(q.w, bcur.w, acc[base + 3][3]);
    SADQ(a0c, 0) SADQ(a1c, 4) SADQ(a2c, 8) SADQ(a3c, 12)
#undef SADQ
    a0c = a0n; a1c = a1n; a2c = a2n; a3c = a3n;
    bcur = bnext;
  }

#pragma unroll
  for (int r = 0; r < 16; ++r) {
    unsigned p0 = (acc[r][0] > 65535u ? 65535u : acc[r][0]) |
                  ((acc[r][1] > 65535u ? 65535u : acc[r][1]) << 16);
    unsigned p1 = (acc[r][2] > 65535u ? 65535u : acc[r][2]) |
                  ((acc[r][3] > 65535u ? 65535u : acc[r][3]) << 16);
    *(uint2*)(out + (size_t)(iw + r) * N + j0 + 4 * lane) = make_uint2(p0, p1);
  }
}

// ============ FAST PATH: 3 dispatches ============
// prep also zeroes out[0] (block (0,0) thread 0) — replaces the memset
// dispatch; stream order guarantees it precedes topk_loss's atomics.
__global__ __launch_bounds__(256) void prep_kernel(
    const float* __restrict__ gt, const float* __restrict__ lat_test,
    const float* __restrict__ lat_train, const float* __restrict__ W,
    const float* __restrict__ bias, unsigned* __restrict__ Gq,
    unsigned* __restrict__ Aq, unsigned* __restrict__ Tq,
    float* __restrict__ out) {
  const int which = blockIdx.y;
  unsigned* __restrict__ dst = which == 0 ? Gq : (which == 1 ? Aq : Tq);
  const int r0 = blockIdx.x * 8;
  const int t = threadIdx.x;
  if (which == 0 && blockIdx.x == 0 && t == 0) out[0] = 0.f;
  __shared__ float ls[8 * L];
  if (which == 0)
    prep_unit<true>(gt, nullptr, W, bias, dst, r0, t, ls);
  else
    prep_unit<false>(nullptr, which == 1 ? lat_test : lat_train, W, bias, dst,
                     r0, t, ls);
}

__global__ __launch_bounds__(256) void dist_sad_kernel(
    const unsigned* __restrict__ Aq, const unsigned* __restrict__ Gq,
    const unsigned* __restrict__ Tq, unsigned short* __restrict__ dist) {
  const int mat = blockIdx.z;
  dist_tile(Aq, mat ? Tq : Gq, dist + (size_t)mat * N * N, blockIdx.x * BI,
            blockIdx.y * BJ, (int)threadIdx.x);
}

__global__ __launch_bounds__(256) void topk_loss_kernel(
    const unsigned short* __restrict__ dist, float* __restrict__ out) {
  const int wave = threadIdx.x >> 6;
  const int lane = threadIdx.x & 63;
  const int row = blockIdx.x * 4 + wave;

  const unsigned* p_pos = (const unsigned*)(dist + (size_t)row * N);
  const unsigned* p_neg = (const unsigned*)(dist + ((size_t)N + row) * N);

  float pos = row_score(p_pos, lane);
  float neg = row_score(p_neg, lane);

  float l = fmaxf(neg - pos, 0.f);
  float h = (l <= 1.f) ? 0.5f * l * l : (l - 0.5f);

  __shared__ float ws[4];
  if (lane == 0) ws[wave] = h;
  __syncthreads();
  if (threadIdx.x == 0) {
    float t = (ws[0] + ws[1] + ws[2] + ws[3]) * (1.0f / (float)N);
    atomicAdd(out, t);
  }
}

// ============ FALLBACK PATH (exact f32, proven) ============
__global__ __launch_bounds__(256) void linear_kernel(
    const float* __restrict__ lat_test, const float* __restrict__ lat_train,
    const float* __restrict__ W, const float* __restrict__ bias,
    float* __restrict__ rec_test, float* __restrict__ rec_train) {
  const float* __restrict__ lat = blockIdx.y ? lat_train : lat_test;
  float* __restrict__ out = blockIdx.y ? rec_train : rec_test;
  const int r0 = blockIdx.x * 8;
  const int t = threadIdx.x;

  __shared__ float ls[8 * L];
  {
    float4 v = *(const float4*)(lat + (size_t)r0 * L + t * 4);
    *(float4*)&ls[t * 4] = v;
  }
  __syncthreads();

  float acc[8][2];
#pragma unroll
  for (int r = 0; r < 8; ++r) { acc[r][0] = 0.f; acc[r][1] = 0.f; }

#pragma unroll 4
  for (int l = 0; l < L; ++l) {
    float w0 = W[l * D + t];
    float w1 = W[l * D + t + 256];
#pragma unroll
    for (int r = 0; r < 8; ++r) {
      float x = ls[r * L + l];
      acc[r][0] = fmaf(x, w0, acc[r][0]);
      acc[r][1] = fmaf(x, w1, acc[r][1]);
    }
  }
  float b0 = bias[t], b1 = bias[t + 256];
#pragma unroll
  for (int r = 0; r < 8; ++r) {
    out[(size_t)(r0 + r) * D + t] = acc[r][0] + b0;
    out[(size_t)(r0 + r) * D + t + 256] = acc[r][1] + b1;
  }
}

__global__ __launch_bounds__(256) void dist_topk_kernel(
    const float* __restrict__ Arec, const float* __restrict__ Bgt,
    const float* __restrict__ Btr, float* __restrict__ cand) {
  const int itile = blockIdx.x;
  const int part = blockIdx.y;
  const int mat = blockIdx.z;
  const float* __restrict__ B = mat ? Btr : Bgt;
  const int i0 = itile * TI;
  const int jbase = part * PARTJ;

  __shared__ float smem[SMEM_FLOATS];
  float* As = smem;
  float* Bs = smem + KD * AS_STRIDE;
  float* distS = smem;

  const int tid = threadIdx.x;
  const int tx = tid & 15;
  const int ty = tid >> 4;
  const int srow = tid >> 1;
  const int shalf = tid & 1;
  const int scol = shalf * 32;

  float tk[16];
#pragma unroll
  for (int k = 0; k < 16; ++k) tk[k] = 3.0e38f;

  for (int jc = 0; jc < PARTJ; jc += TJ) {
    float acc[8][4];
#pragma unroll
    for (int r = 0; r < 8; ++r)
#pragma unroll
      for (int c = 0; c < 4; ++c) acc[r][c] = 0.f;

    for (int d0 = 0; d0 < D; d0 += KD) {
      __syncthreads();
#pragma unroll
      for (int s = 0; s < 4; ++s) {
        int f4 = tid + s * 256;
        int r = f4 >> 3;
        int c4 = f4 & 7;
        float4 v = *(const float4*)(Arec + (size_t)(i0 + r) * D + d0 + c4 * 4);
        As[(4 * c4 + 0) * AS_STRIDE + r] = v.x;
        As[(4 * c4 + 1) * AS_STRIDE + r] = v.y;
        As[(4 * c4 + 2) * AS_STRIDE + r] = v.z;
        As[(4 * c4 + 3) * AS_STRIDE + r] = v.w;
      }
#pragma unroll
      for (int s = 0; s < 2; ++s) {
        int f4 = tid + s * 256;
        int r = f4 >> 3;
        int c4 = f4 & 7;
        float4 v = *(const float4*)(B + (size_t)(jbase + jc + r) * D + d0 + c4 * 4);
        Bs[(4 * c4 + 0) * BS_STRIDE + r] = v.x;
        Bs[(4 * c4 + 1) * BS_STRIDE + r] = v.y;
        Bs[(4 * c4 + 2) * BS_STRIDE + r] = v.z;
        Bs[(4 * c4 + 3) * BS_STRIDE + r] = v.w;
      }
      __syncthreads();

#pragma unroll
      for (int d = 0; d < KD; ++d) {
        float4 a0 = *(const float4*)&As[d * AS_STRIDE + 8 * ty];
        float4 a1 = *(const float4*)&As[d * AS_STRIDE + 8 * ty + 4];
        float4 bv4 = *(const float4*)&Bs[d * BS_STRIDE + 4 * tx];
        float av[8] = {a0.x, a0.y, a0.z, a0.w, a1.x, a1.y, a1.z, a1.w};
        float bv[4] = {bv4.x, bv4.y, bv4.z, bv4.w};
#pragma unroll
        for (int r = 0; r < 8; ++r)
#pragma unroll
          for (int c = 0; c < 4; ++c) acc[r][c] += __builtin_fabsf(av[r] - bv[c]);
      }
    }

    __syncthreads();
#pragma unroll
    for (int r = 0; r < 8; ++r)
      *(float4*)&distS[(8 * ty + r) * DS_STRIDE + 4 * tx] =
          make_float4(acc[r][0], acc[r][1], acc[r][2], acc[r][3]);
    __syncthreads();

#pragma unroll 1
    for (int j4 = 0; j4 < 8; ++j4) {
      float4 v = *(const float4*)&distS[srow * DS_STRIDE + scol + j4 * 4];
      if (v.x < tk[15]) topk_insert(tk, v.x);
      if (v.y < tk[15]) topk_insert(tk, v.y);
      if (v.z < tk[15]) topk_insert(tk, v.z);
      if (v.w < tk[15]) topk_insert(tk, v.w);
    }
  }

  __syncthreads();
  float* mergeS = smem;
#pragma unroll
  for (int k4 = 0; k4 < 4; ++k4)
    *(float4*)&mergeS[srow * 32 + shalf * 16 + k4 * 4] =
        make_float4(tk[k4 * 4], tk[k4 * 4 + 1], tk[k4 * 4 + 2], tk[k4 * 4 + 3]);
  __syncthreads();

  if (tid < TI) {
    const float* LA = &mergeS[tid * 32];
    const float* LB = LA + 16;
    const int row = i0 + tid;
    float* dst = cand + ((size_t)((mat * PARTS + part) * N) + row) * 16;
    int ia = 0, ib = 0;
#pragma unroll 1
    for (int k = 0; k < 16; ++k) {
      float a = LA[ia < 16 ? ia : 15];
      float b = LB[ib < 16 ? ib : 15];
      bool takeA = (ib >= 16) || (ia < 16 && a <= b);
      dst[k] = takeA ? a : b;
      ia += takeA ? 1 : 0;
      ib += takeA ? 0 : 1;
    }
  }
}

__global__ __launch_bounds__(256) void merge_kernel(
    const float* __restrict__ cand, float* __restrict__ scores) {
  const int gid = blockIdx.x * 256 + threadIdx.x;
  if (gid >= 2 * N) return;
  const int m = gid >> 12;
  const int row = gid & (N - 1);

  float tk[16];
#pragma unroll
  for (int k = 0; k < 16; ++k) tk[k] = 3.0e38f;

  for (int p = 0; p < PARTS; ++p) {
    const float* lp = cand + ((size_t)((m * PARTS + p) * N) + row) * 16;
#pragma unroll 1
    for (int k = 0; k < 16; ++k) {
      float v = lp[k];
      if (v >= tk[15]) break;
      topk_insert(tk, v);
    }
  }
  float s = 0.f;
#pragma unroll
  for (int k = 0; k < 16; ++k) s += 1.0f / tk[k];
  scores[(size_t)m * N + row] = s * (1.0f / 16.0f);
}

__global__ __launch_bounds__(256) void loss_kernel(
    const float* __restrict__ scores, float* __restrict__ out) {
  const int tid = threadIdx.x;
  float s = 0.f;
  for (int i = tid; i < N; i += 256) {
    float l = scores[N + i] - scores[i];
    l = fmaxf(l, 0.f);
    s += (l <= 1.f) ? 0.5f * l * l : (l - 0.5f);
  }
#pragma unroll
  for (int off = 32; off > 0; off >>= 1) s += __shfl_down(s, off, 64);
  __shared__ float ws[4];
  if ((tid & 63) == 0) ws[tid >> 6] = s;
  __syncthreads();
  if (tid == 0) {
    float t = ws[0] + ws[1] + ws[2] + ws[3];
    out[0] = t * (1.0f / (float)N);
  }
}

extern "C" void kernel_launch(void* const* d_in, const int* in_sizes, int n_in,
                              void* d_out, int out_size, void* d_ws, size_t ws_size,
                              hipStream_t stream) {
  const float* gt_vals = (const float*)d_in[0];
  const float* train_latent = (const float*)d_in[1];
  const float* test_latent = (const float*)d_in[2];
  const float* W = (const float*)d_in[3];
  const float* b = (const float*)d_in[4];
  float* out = (float*)d_out;

  char* ws = (char*)d_ws;
  const size_t MB = 1048576;
  const size_t REC = 8 * MB;
  const size_t NEED_FAST = 80 * MB;

  if (ws_size >= NEED_FAST) {
    // layout: [0,2M) Aq(test), [2,4M) Tq(train), [4,6M) Gq(gt),
    // [8M,72M) dist u16 (2 * 4096^2 * 2B = 64 MiB).
    unsigned* Aq = (unsigned*)(ws);
    unsigned* Tq = (unsigned*)(ws + 2 * MB);
    unsigned* Gq = (unsigned*)(ws + 4 * MB);
    unsigned short* dist16 = (unsigned short*)(ws + 8 * MB);

    prep_kernel<<<dim3(N / 8, 3), 256, 0, stream>>>(
        gt_vals, test_latent, train_latent, W, b, Gq, Aq, Tq, out);
    dist_sad_kernel<<<dim3(N / BI, N / BJ, 2), 256, 0, stream>>>(
        Aq, Gq, Tq, dist16);
    topk_loss_kernel<<<N / 4, 256, 0, stream>>>(dist16, out);
  } else {
    float* rec_test = (float*)(ws);
    float* rec_train = (float*)(ws + REC);
    float* cand = (float*)(ws + 2 * REC);                 // 8 MB
    float* scores = (float*)(ws + 2 * REC + 8388608);     // 32 KB
    linear_kernel<<<dim3(N / 8, 2), 256, 0, stream>>>(
        test_latent, train_latent, W, b, rec_test, rec_train);
    dist_topk_kernel<<<dim3(N / TI, PARTS, 2), 256, 0, stream>>>(
        rec_test, gt_vals, rec_train, cand);
    merge_kernel<<<(2 * N) / 256, 256, 0, stream>>>(cand, scores);
    loss_kernel<<<1, 256, 0, stream>>>(scores, out);
  }
}